// Round 3
// baseline (565.630 us; speedup 1.0000x reference)
//
#include <hip/hip_runtime.h>
#include <hip/hip_bf16.h>

// ScaleNet gated residual block, MI355X — bf16 MFMA implicit GEMM.
//  K0w wcvt       : mask weights f32 -> f64, layout [c][mask(2)][tap(9)]
//  K0a mask_part  : tap-decomposed channel reduction -> z partials (f64, ws)
//  K0b mask_reduce: 9-point stencil sum of z + bias, threshold -> m1, m2
//  K1 transpose   : x NCHW f32 -> xb NHWC bf16 (stored in d_out scratch)
//  K2 pack        : w1,w2 OIHW f32 -> B-frag-ready packed bf16
//  K3 conv_mfma<1>: conv1 + BN1 + ReLU + *m1 -> tmp NHWC bf16 (ws)
//  K4 conv_mfma<0>: conv2 + BN2 + *m2 + residual + ReLU -> d_out NCHW f32
//
// R3: per-gs stall ~700cy = B-load latency (L2 misses to HBM: FETCH excess
//     174MB ~= 10% of 1.76GB weight re-reads). B prefetch depth 1 -> 2
//     (3-stage circular buf), gs-loop fully unrolled (rotation = renaming).

#define NB 32
#define C  256
#define H  56
#define W  56
#define HW (H*W)          // 3136 = 49*64
#define NBHW (NB*HW)      // 100352
#define EPSV 1e-5f
#define WELEM (C*C*9)     // 589824 packed elements per conv
#define MSPL 2            // mask split-K over channels
#define MCH (C/MSPL)      // 128 channels per split

typedef __hip_bfloat16 bf16;
typedef __attribute__((ext_vector_type(8))) short  bf16x8;
typedef __attribute__((ext_vector_type(4))) float  floatx4;

// ---------------- K0w: mask weights f32 -> f64 ------------------------------
__global__ __launch_bounds__(128) void wcvt_kernel(
    const float* __restrict__ wm1, const float* __restrict__ wm2,
    double* __restrict__ wd)
{
    int i = blockIdx.x * 128 + threadIdx.x;   // 0 .. C*18-1
    if (i >= C * 18) return;
    int c = i / 18;
    int r = i - c * 18;
    int m = r / 9;
    int t = r - 9 * m;
    const float* src = m ? wm2 : wm1;
    wd[i] = (double)src[c * 9 + t];
}

// ---------------- K0a: tap-decomposed mask partials -------------------------
__global__ __launch_bounds__(128) void mask_part_kernel(
    const float* __restrict__ x, const double* __restrict__ wd,
    double* __restrict__ z)
{
    int pixb  = blockIdx.x >> 1;              // 784 pixel-blocks of 128
    int split = blockIdx.x & 1;
    int idx = pixb * 128 + threadIdx.x;       // pixel id, exact (100352 total)
    int n  = idx / HW;
    int hw = idx - n * HW;

    const float*  xp = x  + (size_t)n * C * HW + (size_t)split * MCH * HW + hw;
    const double* wp = wd + (size_t)split * MCH * 18;

    double acc[18];
    #pragma unroll
    for (int j = 0; j < 18; ++j) acc[j] = 0.0;

    for (int c = 0; c < MCH; ++c) {
        double xv = (double)xp[(size_t)c * HW];   // coalesced across lanes
        const double* w = wp + c * 18;            // wave-uniform -> s_load
        #pragma unroll
        for (int j = 0; j < 18; ++j)
            acc[j] += xv * w[j];
    }

    #pragma unroll
    for (int j = 0; j < 18; ++j)
        z[(size_t)(split * 18 + j) * NBHW + idx] = acc[j];
}

// ---------------- K0b: stencil-sum partials, threshold ----------------------
__global__ __launch_bounds__(256) void mask_reduce_kernel(
    const double* __restrict__ z,
    const float* __restrict__ bm1, const float* __restrict__ bm2,
    float* __restrict__ m1, float* __restrict__ m2)
{
    int idx = blockIdx.x * 256 + threadIdx.x;
    int n  = idx / HW;
    int hw = idx - n * HW;
    int h  = hw / W;
    int w_ = hw - h * W;

    double a1 = (double)bm1[0], a2 = (double)bm2[0];
    #pragma unroll
    for (int ky = 0; ky < 3; ++ky) {
        int y = h + ky - 1;
        if ((unsigned)y >= (unsigned)H) continue;
        #pragma unroll
        for (int kx = 0; kx < 3; ++kx) {
            int xx = w_ + kx - 1;
            if ((unsigned)xx >= (unsigned)W) continue;
            int t = ky * 3 + kx;
            size_t q = (size_t)n * HW + (size_t)y * W + xx;
            a1 += z[(size_t)(0 * 18 + 0 * 9 + t) * NBHW + q]
                + z[(size_t)(1 * 18 + 0 * 9 + t) * NBHW + q];
            a2 += z[(size_t)(0 * 18 + 1 * 9 + t) * NBHW + q]
                + z[(size_t)(1 * 18 + 1 * 9 + t) * NBHW + q];
        }
    }
    m1[idx] = (a1 > 0.0) ? 1.0f : 0.0f;   // sigmoid(z)>0.5 <=> z>0
    m2[idx] = (a2 > 0.0) ? 1.0f : 0.0f;
}

// ---------------- K1: NCHW f32 -> NHWC bf16 ---------------------------------
__global__ __launch_bounds__(256) void transpose_kernel(
    const float* __restrict__ x, bf16* __restrict__ xb)
{
    __shared__ float tile[64][65];
    int bid = blockIdx.x;             // 32 * 4 * 49
    int pt = bid % 49; bid /= 49;
    int ct = bid % 4;  int n = bid / 4;
    int p0 = pt * 64, c0 = ct * 64;
    int tl = threadIdx.x & 63;
    int tg = threadIdx.x >> 6;        // 0..3
    const float* xp = x + ((size_t)(n*C + c0) * HW) + p0;
    #pragma unroll
    for (int i = 0; i < 16; ++i) {
        int cl = tg*16 + i;
        tile[cl][tl] = xp[(size_t)cl * HW + tl];
    }
    __syncthreads();
    bf16* op = xb + ((size_t)(n*HW + p0) * C) + c0;
    #pragma unroll
    for (int i = 0; i < 16; ++i) {
        int pl = tg*16 + i;
        op[(size_t)pl * C + tl] = __float2bfloat16(tile[tl][pl]);
    }
}

// ---------------- K2: pack weights into B-frag order ------------------------
// layout: [tap(9)][kstep(8)][ntile(16)][lane(64)][8 ci]  (16B per lane)
__global__ __launch_bounds__(256) void pack_kernel(
    const float* __restrict__ w1, const float* __restrict__ w2,
    bf16* __restrict__ w1p, bf16* __restrict__ w2p)
{
    int idx = blockIdx.x * 256 + threadIdx.x;       // 0 .. 2*WELEM-1
    const float* src = (idx < WELEM) ? w1 : w2;
    bf16* dst        = (idx < WELEM) ? w1p : w2p;
    int f = (idx < WELEM) ? idx : idx - WELEM;
    int e  = f & 7;
    int O  = f >> 3;
    int L  = O & 63;
    int j  = (O >> 6) & 15;
    int ks = (O >> 10) & 7;
    int t  = O >> 13;
    int co = j*16 + (L & 15);
    int ci = ks*32 + ((L >> 4) & 3)*8 + e;
    dst[f] = __float2bfloat16(src[((size_t)co*C + ci)*9 + t]);
}

// ---------------- K3/K4: MFMA implicit-GEMM conv ----------------------------
// block: 64 pixels (8x8 tile) x 256 co, 4 waves (64 co each), K chunked 128.
// B (L2/HBM) prefetched 2 gs ahead (3-stage circ buf); A (LDS) 1 gs ahead.
// gs-loop fully unrolled so stage rotation is register renaming, not v_movs.
template<bool FIRST>
__global__ __launch_bounds__(256, 3) void conv_mfma(
    const bf16* __restrict__ inb,    // NHWC bf16
    const bf16* __restrict__ wp,     // packed weights
    const float* __restrict__ g,  const float* __restrict__ b,
    const float* __restrict__ mu, const float* __restrict__ vv,
    const float* __restrict__ mask,  // [NB][HW] 0/1
    const float* __restrict__ xres,  // NCHW f32 (SECOND)
    bf16* __restrict__ outb,         // FIRST: tmp NHWC bf16
    float* __restrict__ outf)        // SECOND: NCHW f32
{
    __shared__ uint4 patch4[1700];   // 100 pos * (128 ci + 8 pad) shorts = 27.2 KB
    __shared__ float msk[64];
    short* patch = (short*)patch4;

    int bid  = blockIdx.x;
    int tile = bid % 49;
    int n    = bid / 49;
    int y0 = (tile / 7) * 8;
    int x0 = (tile % 7) * 8;

    int tid = threadIdx.x;
    int L   = tid & 63;
    int wv  = tid >> 6;

    if (tid < 64) {
        int pr = tid >> 3, pc = tid & 7;
        msk[tid] = mask[(size_t)n*HW + (y0+pr)*W + (x0+pc)];
    }

    // per-lane A-fragment base offsets (padded stride 136 shorts/position)
    int m  = L & 15;
    int kb = L >> 4;
    int abase[4];
    #pragma unroll
    for (int mi = 0; mi < 4; ++mi) {
        int p   = mi*16 + m;
        int pos = (p >> 3)*10 + (p & 7);
        abase[mi] = pos*136 + kb*8;
    }

    // per-lane B base pointer (16B per lane within each [64-lane] group)
    const bf16* wpL = wp + (size_t)L * 8;

    floatx4 acc[4][4];
    #pragma unroll
    for (int mi = 0; mi < 4; ++mi)
        #pragma unroll
        for (int jj = 0; jj < 4; ++jj)
            acc[mi][jj] = (floatx4){0.f, 0.f, 0.f, 0.f};

    const size_t img_base = (size_t)n * HW * C;

    for (int ck = 0; ck < 2; ++ck) {
        if (ck) __syncthreads();                 // LDS reuse fence
        // ---- stage 10x10 halo patch, 128-ci chunk, into LDS ----
        for (int S = tid; S < 1600; S += 256) {
            int q   = S & 15;
            int pos = S >> 4;
            int r = pos / 10, c = pos - (pos/10)*10;
            int y  = y0 + r - 1;
            int xx = x0 + c - 1;
            uint4 val = make_uint4(0u, 0u, 0u, 0u);
            if ((unsigned)y < (unsigned)H && (unsigned)xx < (unsigned)W)
                val = *(const uint4*)(inb + img_base + (size_t)(y*W + xx)*C + ck*128 + q*8);
            patch4[pos*17 + q] = val;
        }
        __syncthreads();

        // ---- K-loop: 9 taps x 4 ksteps; B depth-2, A depth-1 prefetch ----
        bf16x8 bbuf[3][4];
        bf16x8 abuf[2][4];
        {
            // prologue: B for gs=0,1 ; A for gs=0
            #pragma unroll
            for (int pg = 0; pg < 2; ++pg) {
                int t0 = pg >> 2, s0 = pg & 3;     // pg<4 -> t0=0
                int ks0 = ck*4 + s0;
                #pragma unroll
                for (int jj = 0; jj < 4; ++jj) {
                    int jgl = wv*4 + jj;
                    bbuf[pg][jj] = *(const bf16x8*)(wpL + ((size_t)((t0*8 + ks0)*16 + jgl)*64)*8);
                }
            }
            #pragma unroll
            for (int mi = 0; mi < 4; ++mi)
                abuf[0][mi] = *(const bf16x8*)(patch + abase[mi]);   // gs=0: aoff=0
        }
        #pragma unroll
        for (int gs = 0; gs < 36; ++gs) {
            const int cur = gs % 3;
            const int ac  = gs & 1;
            if (gs + 2 < 36) {                    // B prefetch, 2 ahead
                const int g2 = gs + 2;
                const int t2 = g2 >> 2, s2 = g2 & 3;
                const int ks2 = ck*4 + s2;
                const int dst = g2 % 3;
                #pragma unroll
                for (int jj = 0; jj < 4; ++jj) {
                    int jgl = wv*4 + jj;
                    bbuf[dst][jj] = *(const bf16x8*)(wpL + ((size_t)((t2*8 + ks2)*16 + jgl)*64)*8);
                }
            }
            if (gs + 1 < 36) {                    // A prefetch, 1 ahead
                const int g1 = gs + 1;
                const int t1 = g1 >> 2, s1 = g1 & 3;
                const int ky1 = t1 / 3;
                const int dt1 = ky1*10 + (t1 - ky1*3);
                const int aoff1 = dt1*136 + s1*32;
                #pragma unroll
                for (int mi = 0; mi < 4; ++mi)
                    abuf[ac ^ 1][mi] = *(const bf16x8*)(patch + abase[mi] + aoff1);
            }
            #pragma unroll
            for (int mi = 0; mi < 4; ++mi)
                #pragma unroll
                for (int jj = 0; jj < 4; ++jj)
                    acc[mi][jj] = __builtin_amdgcn_mfma_f32_16x16x32_bf16(
                        abuf[ac][mi], bbuf[cur][jj], acc[mi][jj], 0, 0, 0);
        }
    }

    // ---- epilogue ----
    int quad  = L >> 4;
    int wbase = wv * 64;
    #pragma unroll
    for (int jj = 0; jj < 4; ++jj) {
        int co = wbase + jj*16 + (L & 15);
        float s_ = g[co] * rsqrtf(vv[co] + EPSV);
        float t_ = b[co] - mu[co] * s_;
        #pragma unroll
        for (int mi = 0; mi < 4; ++mi) {
            int pbase = mi*16 + quad*4;
            if (FIRST) {
                #pragma unroll
                for (int r = 0; r < 4; ++r) {
                    int p = pbase + r;
                    float v = acc[mi][jj][r] * s_ + t_;
                    v = fmaxf(v, 0.f) * msk[p];
                    int pg = (y0 + (p >> 3))*W + (x0 + (p & 7));
                    outb[img_base + (size_t)pg*C + co] = __float2bfloat16(v);
                }
            } else {
                int pg = (y0 + (pbase >> 3))*W + (x0 + (pbase & 7));
                size_t oidx = ((size_t)(n*C + co))*HW + pg;
                floatx4 xr = *(const floatx4*)(xres + oidx);
                floatx4 ov;
                #pragma unroll
                for (int r = 0; r < 4; ++r) {
                    float v = acc[mi][jj][r] * s_ + t_;
                    v = v * msk[pbase + r] + xr[r];
                    ov[r] = fmaxf(v, 0.f);
                }
                *(floatx4*)(outf + oidx) = ov;
            }
        }
    }
}

extern "C" void kernel_launch(void* const* d_in, const int* in_sizes, int n_in,
                              void* d_out, int out_size, void* d_ws, size_t ws_size,
                              hipStream_t stream) {
    const float* x   = (const float*)d_in[0];
    const float* w1  = (const float*)d_in[1];
    const float* w2  = (const float*)d_in[2];
    const float* g1  = (const float*)d_in[3];
    const float* b1  = (const float*)d_in[4];
    const float* mu1 = (const float*)d_in[5];
    const float* v1  = (const float*)d_in[6];
    const float* g2  = (const float*)d_in[7];
    const float* b2  = (const float*)d_in[8];
    const float* mu2 = (const float*)d_in[9];
    const float* v2  = (const float*)d_in[10];
    const float* wm1 = (const float*)d_in[11];
    const float* bm1 = (const float*)d_in[12];
    const float* wm2 = (const float*)d_in[13];
    const float* bm2 = (const float*)d_in[14];
    float* out = (float*)d_out;

    // workspace (~83.5 MB):
    float* m1   = (float*)d_ws;                      // NB*HW
    float* m2   = m1 + (size_t)NBHW;                 // NB*HW
    bf16*  w1p  = (bf16*)(m2 + (size_t)NBHW);        // WELEM
    bf16*  w2p  = w1p + WELEM;                       // WELEM
    bf16*  tmpb = w2p + WELEM;                       // NB*HW*C bf16
    double* z   = (double*)(tmpb + (size_t)NBHW*C);  // MSPL*2*9*NBHW f64 = 28.9 MB
    double* wd  = z + (size_t)MSPL*18*NBHW;          // C*18 f64
    // xb (NHWC bf16, 51.4 MB) lives in d_out: dead until conv2's epilogue.
    bf16*  xb   = (bf16*)d_out;

    wcvt_kernel<<<(C*18 + 127)/128, 128, 0, stream>>>(wm1, wm2, wd);
    mask_part_kernel<<<(NBHW/128)*MSPL, 128, 0, stream>>>(x, wd, z);
    mask_reduce_kernel<<<NBHW/256, 256, 0, stream>>>(z, bm1, bm2, m1, m2);
    transpose_kernel<<<NB*4*49, 256, 0, stream>>>(x, xb);
    pack_kernel<<<2*WELEM/256, 256, 0, stream>>>(w1, w2, w1p, w2p);

    const int grid = NB * 49;    // 1568 blocks: 8x8 pixel tile x full co
    conv_mfma<true ><<<grid, 256, 0, stream>>>(
        xb,   w1p, g1, b1, mu1, v1, m1, nullptr, tmpb, nullptr);
    conv_mfma<false><<<grid, 256, 0, stream>>>(
        tmpb, w2p, g2, b2, mu2, v2, m2, x, nullptr, out);
}

// Round 4
// 549.634 us; speedup vs baseline: 1.0291x; 1.0291x over previous
//
#include <hip/hip_runtime.h>
#include <hip/hip_bf16.h>

// ScaleNet gated residual block, MI355X — bf16 MFMA implicit GEMM.
//  K0w wcvt       : mask weights f32 -> f64, layout [c][mask(2)][tap(9)]
//  K0a mask_part  : tap-decomposed channel reduction -> z partials (f64, ws)
//  K0b mask_reduce: 9-point stencil sum of z + bias, threshold -> m1, m2
//  K1 transpose   : x NCHW f32 -> xb NHWC bf16 (stored in d_out scratch)
//  K2 pack        : w1,w2 OIHW f32 -> B-frag-ready packed bf16
//  K3 conv_mfma<1>: conv1 + BN1 + ReLU + *m1 -> tmp NHWC bf16 (ws)
//  K4 conv_mfma<0>: conv2 + BN2 + *m2 + residual + ReLU -> d_out NCHW f32
//
// R4: per-gs stall ~770cy is invariant under prefetch depth & VALU removal;
//     occupancy pinned at 2 blocks/CU. Lever: M-tile 64 -> 128 pixels/block
//     (two 8x8 subtiles, 784 blocks). Same 4 B-loads/gs now feed 32 MFMAs
//     (620cy issue) -> stall amortized 2x; weight L2/HBM re-read traffic
//     halves (1.85 -> 0.93 GB/conv). LDS 54.9 KB/block (2 blocks/CU fits).

#define NB 32
#define C  256
#define H  56
#define W  56
#define HW (H*W)          // 3136 = 49*64
#define NBHW (NB*HW)      // 100352
#define EPSV 1e-5f
#define WELEM (C*C*9)     // 589824 packed elements per conv
#define MSPL 2            // mask split-K over channels
#define MCH (C/MSPL)      // 128 channels per split

typedef __hip_bfloat16 bf16;
typedef __attribute__((ext_vector_type(8))) short  bf16x8;
typedef __attribute__((ext_vector_type(4))) float  floatx4;

// ---------------- K0w: mask weights f32 -> f64 ------------------------------
__global__ __launch_bounds__(128) void wcvt_kernel(
    const float* __restrict__ wm1, const float* __restrict__ wm2,
    double* __restrict__ wd)
{
    int i = blockIdx.x * 128 + threadIdx.x;   // 0 .. C*18-1
    if (i >= C * 18) return;
    int c = i / 18;
    int r = i - c * 18;
    int m = r / 9;
    int t = r - 9 * m;
    const float* src = m ? wm2 : wm1;
    wd[i] = (double)src[c * 9 + t];
}

// ---------------- K0a: tap-decomposed mask partials -------------------------
__global__ __launch_bounds__(128) void mask_part_kernel(
    const float* __restrict__ x, const double* __restrict__ wd,
    double* __restrict__ z)
{
    int pixb  = blockIdx.x >> 1;              // 784 pixel-blocks of 128
    int split = blockIdx.x & 1;
    int idx = pixb * 128 + threadIdx.x;       // pixel id, exact (100352 total)
    int n  = idx / HW;
    int hw = idx - n * HW;

    const float*  xp = x  + (size_t)n * C * HW + (size_t)split * MCH * HW + hw;
    const double* wp = wd + (size_t)split * MCH * 18;

    double acc[18];
    #pragma unroll
    for (int j = 0; j < 18; ++j) acc[j] = 0.0;

    for (int c = 0; c < MCH; ++c) {
        double xv = (double)xp[(size_t)c * HW];   // coalesced across lanes
        const double* w = wp + c * 18;            // wave-uniform -> s_load
        #pragma unroll
        for (int j = 0; j < 18; ++j)
            acc[j] += xv * w[j];
    }

    #pragma unroll
    for (int j = 0; j < 18; ++j)
        z[(size_t)(split * 18 + j) * NBHW + idx] = acc[j];
}

// ---------------- K0b: stencil-sum partials, threshold ----------------------
__global__ __launch_bounds__(256) void mask_reduce_kernel(
    const double* __restrict__ z,
    const float* __restrict__ bm1, const float* __restrict__ bm2,
    float* __restrict__ m1, float* __restrict__ m2)
{
    int idx = blockIdx.x * 256 + threadIdx.x;
    int n  = idx / HW;
    int hw = idx - n * HW;
    int h  = hw / W;
    int w_ = hw - h * W;

    double a1 = (double)bm1[0], a2 = (double)bm2[0];
    #pragma unroll
    for (int ky = 0; ky < 3; ++ky) {
        int y = h + ky - 1;
        if ((unsigned)y >= (unsigned)H) continue;
        #pragma unroll
        for (int kx = 0; kx < 3; ++kx) {
            int xx = w_ + kx - 1;
            if ((unsigned)xx >= (unsigned)W) continue;
            int t = ky * 3 + kx;
            size_t q = (size_t)n * HW + (size_t)y * W + xx;
            a1 += z[(size_t)(0 * 18 + 0 * 9 + t) * NBHW + q]
                + z[(size_t)(1 * 18 + 0 * 9 + t) * NBHW + q];
            a2 += z[(size_t)(0 * 18 + 1 * 9 + t) * NBHW + q]
                + z[(size_t)(1 * 18 + 1 * 9 + t) * NBHW + q];
        }
    }
    m1[idx] = (a1 > 0.0) ? 1.0f : 0.0f;   // sigmoid(z)>0.5 <=> z>0
    m2[idx] = (a2 > 0.0) ? 1.0f : 0.0f;
}

// ---------------- K1: NCHW f32 -> NHWC bf16 ---------------------------------
__global__ __launch_bounds__(256) void transpose_kernel(
    const float* __restrict__ x, bf16* __restrict__ xb)
{
    __shared__ float tile[64][65];
    int bid = blockIdx.x;             // 32 * 4 * 49
    int pt = bid % 49; bid /= 49;
    int ct = bid % 4;  int n = bid / 4;
    int p0 = pt * 64, c0 = ct * 64;
    int tl = threadIdx.x & 63;
    int tg = threadIdx.x >> 6;        // 0..3
    const float* xp = x + ((size_t)(n*C + c0) * HW) + p0;
    #pragma unroll
    for (int i = 0; i < 16; ++i) {
        int cl = tg*16 + i;
        tile[cl][tl] = xp[(size_t)cl * HW + tl];
    }
    __syncthreads();
    bf16* op = xb + ((size_t)(n*HW + p0) * C) + c0;
    #pragma unroll
    for (int i = 0; i < 16; ++i) {
        int pl = tg*16 + i;
        op[(size_t)pl * C + tl] = __float2bfloat16(tile[tl][pl]);
    }
}

// ---------------- K2: pack weights into B-frag order ------------------------
// layout: [tap(9)][kstep(8)][ntile(16)][lane(64)][8 ci]  (16B per lane)
__global__ __launch_bounds__(256) void pack_kernel(
    const float* __restrict__ w1, const float* __restrict__ w2,
    bf16* __restrict__ w1p, bf16* __restrict__ w2p)
{
    int idx = blockIdx.x * 256 + threadIdx.x;       // 0 .. 2*WELEM-1
    const float* src = (idx < WELEM) ? w1 : w2;
    bf16* dst        = (idx < WELEM) ? w1p : w2p;
    int f = (idx < WELEM) ? idx : idx - WELEM;
    int e  = f & 7;
    int O  = f >> 3;
    int L  = O & 63;
    int j  = (O >> 6) & 15;
    int ks = (O >> 10) & 7;
    int t  = O >> 13;
    int co = j*16 + (L & 15);
    int ci = ks*32 + ((L >> 4) & 3)*8 + e;
    dst[f] = __float2bfloat16(src[((size_t)co*C + ci)*9 + t]);
}

// ---------------- K3/K4: MFMA implicit-GEMM conv ----------------------------
// block: 128 pixels (two 8x8 subtiles) x 256 co, 4 waves (64 co each).
// Per gs: 4 B-loads (global, shared across 32 MFMAs) + 8 A ds_reads.
// A+B register double-buffered 1 gs ahead (R2-proven schedule).
template<bool FIRST>
__global__ __launch_bounds__(256, 2) void conv_mfma(
    const bf16* __restrict__ inb,    // NHWC bf16
    const bf16* __restrict__ wp,     // packed weights
    const float* __restrict__ g,  const float* __restrict__ b,
    const float* __restrict__ mu, const float* __restrict__ vv,
    const float* __restrict__ mask,  // [NB][HW] 0/1
    const float* __restrict__ xres,  // NCHW f32 (SECOND)
    bf16* __restrict__ outb,         // FIRST: tmp NHWC bf16
    float* __restrict__ outf)        // SECOND: NCHW f32
{
    __shared__ uint4 patch4[3400];   // 2 subtiles * 100 pos * 17 uint4 = 54.4 KB
    __shared__ float msk[128];
    short* patch = (short*)patch4;

    int tid = threadIdx.x;
    int L   = tid & 63;
    int wv  = tid >> 6;

    // two flattened (n,tile) ids
    int t0g = blockIdx.x * 2;
    int n_s[2], y0_s[2], x0_s[2];
    size_t ibase_s[2];
    #pragma unroll
    for (int s = 0; s < 2; ++s) {
        int ts = t0g + s;
        int ns = ts / 49;
        int tl = ts - ns * 49;
        n_s[s]  = ns;
        y0_s[s] = (tl / 7) * 8;
        x0_s[s] = (tl % 7) * 8;
        ibase_s[s] = (size_t)ns * HW * C;
    }

    if (tid < 128) {
        int s  = tid >> 6;
        int p  = tid & 63;
        int pr = p >> 3, pc = p & 7;
        msk[tid] = mask[(size_t)n_s[s]*HW + (y0_s[s]+pr)*W + (x0_s[s]+pc)];
    }

    // per-lane A-fragment base offsets (padded stride 136 shorts/position;
    // subtile stride 13600 shorts = 1700 uint4)
    int m  = L & 15;
    int kb = L >> 4;
    int abase[8];
    #pragma unroll
    for (int mi = 0; mi < 8; ++mi) {
        int p   = mi*16 + m;          // 0..127
        int s   = p >> 6;
        int pl  = p & 63;
        int pos = (pl >> 3)*10 + (pl & 7);
        abase[mi] = s*13600 + pos*136 + kb*8;
    }

    floatx4 acc[8][4];
    #pragma unroll
    for (int mi = 0; mi < 8; ++mi)
        #pragma unroll
        for (int jj = 0; jj < 4; ++jj)
            acc[mi][jj] = (floatx4){0.f, 0.f, 0.f, 0.f};

    for (int ck = 0; ck < 2; ++ck) {
        if (ck) __syncthreads();                 // LDS reuse fence
        // ---- stage two 10x10 halo patches, 128-ci chunk, into LDS ----
        for (int S = tid; S < 3200; S += 256) {
            int s   = S >= 1600;
            int r0  = S - s*1600;
            int q   = r0 & 15;
            int pos = r0 >> 4;
            int rr = pos / 10, cc = pos - (pos/10)*10;
            int y  = y0_s[s] + rr - 1;
            int xx = x0_s[s] + cc - 1;
            uint4 val = make_uint4(0u, 0u, 0u, 0u);
            if ((unsigned)y < (unsigned)H && (unsigned)xx < (unsigned)W)
                val = *(const uint4*)(inb + ibase_s[s] + (size_t)(y*W + xx)*C + ck*128 + q*8);
            patch4[s*1700 + pos*17 + q] = val;
        }
        __syncthreads();

        // ---- K-loop: 9 taps x 4 ksteps, A+B register-double-buffered ----
        bf16x8 bcur[4], bnxt[4];
        bf16x8 acur[8], anxt[8];
        {
            int ks0 = ck*4;
            #pragma unroll
            for (int jj = 0; jj < 4; ++jj) {
                int jgl = wv*4 + jj;
                bcur[jj] = *(const bf16x8*)(wp + ((size_t)((0*8 + ks0)*16 + jgl)*64 + L)*8);
            }
            #pragma unroll
            for (int mi = 0; mi < 8; ++mi)
                acur[mi] = *(const bf16x8*)(patch + abase[mi]);   // gs=0: aoff=0
        }
        for (int gs = 0; gs < 36; ++gs) {
            if (gs < 35) {
                int g2 = gs + 1;
                int t2 = g2 >> 2, s2 = g2 & 3;
                int ks2 = ck*4 + s2;
                #pragma unroll
                for (int jj = 0; jj < 4; ++jj) {
                    int jgl = wv*4 + jj;
                    bnxt[jj] = *(const bf16x8*)(wp + ((size_t)((t2*8 + ks2)*16 + jgl)*64 + L)*8);
                }
                int ky2 = t2 / 3;
                int dt2 = ky2*10 + (t2 - ky2*3);
                int aoff2 = dt2*136 + s2*32;
                #pragma unroll
                for (int mi = 0; mi < 8; ++mi)
                    anxt[mi] = *(const bf16x8*)(patch + abase[mi] + aoff2);
            }
            #pragma unroll
            for (int mi = 0; mi < 8; ++mi)
                #pragma unroll
                for (int jj = 0; jj < 4; ++jj)
                    acc[mi][jj] = __builtin_amdgcn_mfma_f32_16x16x32_bf16(
                        acur[mi], bcur[jj], acc[mi][jj], 0, 0, 0);
            #pragma unroll
            for (int jj = 0; jj < 4; ++jj) bcur[jj] = bnxt[jj];
            #pragma unroll
            for (int mi = 0; mi < 8; ++mi) acur[mi] = anxt[mi];
        }
    }

    // ---- epilogue ----
    int quad  = L >> 4;
    int wbase = wv * 64;
    #pragma unroll
    for (int jj = 0; jj < 4; ++jj) {
        int co = wbase + jj*16 + (L & 15);
        float s_ = g[co] * rsqrtf(vv[co] + EPSV);
        float t_ = b[co] - mu[co] * s_;
        #pragma unroll
        for (int mi = 0; mi < 8; ++mi) {
            int pbase = mi*16 + quad*4;       // pixel 0..127; all 4 r same subtile
            int s   = pbase >> 6;
            int pl  = pbase & 63;
            if (FIRST) {
                #pragma unroll
                for (int r = 0; r < 4; ++r) {
                    int p = pl + r;
                    float v = acc[mi][jj][r] * s_ + t_;
                    v = fmaxf(v, 0.f) * msk[pbase + r];
                    int pg = (y0_s[s] + (p >> 3))*W + (x0_s[s] + (p & 7));
                    outb[ibase_s[s] + (size_t)pg*C + co] = __float2bfloat16(v);
                }
            } else {
                int pg = (y0_s[s] + (pl >> 3))*W + (x0_s[s] + (pl & 7));
                size_t oidx = ((size_t)(n_s[s]*C + co))*HW + pg;
                floatx4 xr = *(const floatx4*)(xres + oidx);
                floatx4 ov;
                #pragma unroll
                for (int r = 0; r < 4; ++r) {
                    float v = acc[mi][jj][r] * s_ + t_;
                    v = v * msk[pbase + r] + xr[r];
                    ov[r] = fmaxf(v, 0.f);
                }
                *(floatx4*)(outf + oidx) = ov;
            }
        }
    }
}

extern "C" void kernel_launch(void* const* d_in, const int* in_sizes, int n_in,
                              void* d_out, int out_size, void* d_ws, size_t ws_size,
                              hipStream_t stream) {
    const float* x   = (const float*)d_in[0];
    const float* w1  = (const float*)d_in[1];
    const float* w2  = (const float*)d_in[2];
    const float* g1  = (const float*)d_in[3];
    const float* b1  = (const float*)d_in[4];
    const float* mu1 = (const float*)d_in[5];
    const float* v1  = (const float*)d_in[6];
    const float* g2  = (const float*)d_in[7];
    const float* b2  = (const float*)d_in[8];
    const float* mu2 = (const float*)d_in[9];
    const float* v2  = (const float*)d_in[10];
    const float* wm1 = (const float*)d_in[11];
    const float* bm1 = (const float*)d_in[12];
    const float* wm2 = (const float*)d_in[13];
    const float* bm2 = (const float*)d_in[14];
    float* out = (float*)d_out;

    // workspace (~83.5 MB):
    float* m1   = (float*)d_ws;                      // NB*HW
    float* m2   = m1 + (size_t)NBHW;                 // NB*HW
    bf16*  w1p  = (bf16*)(m2 + (size_t)NBHW);        // WELEM
    bf16*  w2p  = w1p + WELEM;                       // WELEM
    bf16*  tmpb = w2p + WELEM;                       // NB*HW*C bf16
    double* z   = (double*)(tmpb + (size_t)NBHW*C);  // MSPL*2*9*NBHW f64 = 28.9 MB
    double* wd  = z + (size_t)MSPL*18*NBHW;          // C*18 f64
    // xb (NHWC bf16, 51.4 MB) lives in d_out: dead until conv2's epilogue.
    bf16*  xb   = (bf16*)d_out;

    wcvt_kernel<<<(C*18 + 127)/128, 128, 0, stream>>>(wm1, wm2, wd);
    mask_part_kernel<<<(NBHW/128)*MSPL, 128, 0, stream>>>(x, wd, z);
    mask_reduce_kernel<<<NBHW/256, 256, 0, stream>>>(z, bm1, bm2, m1, m2);
    transpose_kernel<<<NB*4*49, 256, 0, stream>>>(x, xb);
    pack_kernel<<<2*WELEM/256, 256, 0, stream>>>(w1, w2, w1p, w2p);

    const int grid = NBHW / 128;    // 784 blocks: two 8x8 subtiles x full co
    conv_mfma<true ><<<grid, 256, 0, stream>>>(
        xb,   w1p, g1, b1, mu1, v1, m1, nullptr, tmpb, nullptr);
    conv_mfma<false><<<grid, 256, 0, stream>>>(
        tmpb, w2p, g2, b2, mu2, v2, m2, x, nullptr, out);
}